// Round 7
// baseline (281.753 us; speedup 1.0000x reference)
//
#include <hip/hip_runtime.h>

#define RMAX 60
#define KTAPS 121          // 2*RMAX+1
#define WPH 160            // hpass weights: center 79 (taps at [19,139]), zeros outside
#define WPV 160            // vpass weights: center 76 (taps at [16,136]), zeros outside
#define NC 3
#define NH 256
#define NW 256
#define NPLANE (64 * NC)   // 192
#define NITEMS_H (NPLANE * 64)   // 4-row tiles per wave
#define NITEMS_V (NPLANE * 16)   // 16-row tiles per wave

__device__ __forceinline__ int refl(int q) {
    // jnp.pad mode='reflect'; valid for q in (-NH, 2*NH-1). Branch-free.
    q = q < 0 ? -q : q;
    int d = (NH - 1) - q;
    d = d < 0 ? -d : d;
    return (NH - 1) - d;
}

// One block (1 wave) per sample: normalized kernel in two padded layouts.
__global__ void wgen(const int* __restrict__ steps, const float* __restrict__ sigmas,
                     float* __restrict__ wpadH, float* __restrict__ wpadV) {
    const int b = blockIdx.x;
    const int t = threadIdx.x;               // 0..63
    const float sg = sigmas[steps[b]];
    const float r = ceilf(3.0f * sg);
    const float inv2s2 = 0.5f / (sg * sg);
    const float o0 = (float)(t - RMAX);                  // tap t-60
    float w0 = (fabsf(o0) <= r) ? expf(-o0 * o0 * inv2s2) : 0.0f;
    const float o1 = (float)(t + 4);                     // tap t+4
    const int t1 = t + 64;
    float w1 = (t1 < KTAPS && fabsf(o1) <= r) ? expf(-o1 * o1 * inv2s2) : 0.0f;
    float s = w0 + w1;
#pragma unroll
    for (int off = 32; off > 0; off >>= 1) s += __shfl_down(s, off);
    const float inv = 1.0f / __shfl(s, 0);
    // H layout: center 79. rh[79+o] = tap o. taps occupy [19,139].
    float* rh = wpadH + b * WPH;
    if (t < 19) rh[t] = 0.0f;                          // [0,19)
    rh[19 + t] = w0 * inv;                             // [19,83)  taps -60..3
    rh[83 + t] = w1 * inv;                             // [83,147) taps 4..60, 0 beyond
    if (t < 13) rh[147 + t] = 0.0f;                    // [147,160)
    // V layout: center 76. taps occupy [16,136].
    float* rv = wpadV + b * WPV;
    if (t < 16) rv[t] = 0.0f;                          // [0,16)
    rv[16 + t] = w0 * inv;                             // [16,80)
    rv[80 + t] = w1 * inv;                             // [80,144)
    if (t < 16) rv[144 + t] = 0.0f;                    // [144,160)
}

// Horizontal pass: persistent waves + ticket queue. Item = 4 rows.
// Lane owns 16 consecutive px of one row (4 lanes-groups x 16 lanes).
// Data: float4 chunks from global (L1-cached); weights: wave-uniform global
// reads (scalarize to s_load, SMEM pipe). ZERO LDS.
__global__ __launch_bounds__(256, 4) void hpass(const float* __restrict__ in,
                                                const float* __restrict__ wpadH,
                                                const int* __restrict__ steps,
                                                const float* __restrict__ sigmas,
                                                float* __restrict__ tmp,
                                                unsigned int* __restrict__ tick) {
    const int lane = threadIdx.x & 63;
    for (;;) {
        unsigned int t;
        if (lane == 0) t = atomicAdd(tick, 1u);
        t = (unsigned int)__builtin_amdgcn_readfirstlane((int)t);
        if (t >= NITEMS_H) return;
        const int plane = (int)(t >> 6);
        const int tile  = (int)(t & 63u);
        const int b = plane / NC;
        const float sg = sigmas[steps[b]];
        const int rp = ((int)ceilf(3.0f * sg) + 3) & ~3;
        const int row = tile * 4 + (lane >> 4);
        const int xg = (lane & 15) << 4;
        const float* __restrict__ rowp = in + ((size_t)plane << 16) + ((size_t)row << 8);
        const float* __restrict__ wr = wpadH + b * WPH;     // uniform
        float4 oA = make_float4(0.f, 0.f, 0.f, 0.f), oB = oA, oC = oA, oD = oA;
        const int C = 4 + (rp >> 1);        // float4 input chunks

#define HLOAD(dst, cc) do {                                                   \
    const int p0_ = xg - rp + 4 * (cc);                                       \
    if (p0_ >= 0 && p0_ <= NW - 4) {                                          \
        dst = *(const float4*)(rowp + p0_);                                   \
    } else {                                                                  \
        dst.x = rowp[refl(p0_)];     dst.y = rowp[refl(p0_ + 1)];             \
        dst.z = rowp[refl(p0_ + 2)]; dst.w = rowp[refl(p0_ + 3)];             \
    }                                                                         \
} while (0)

#define GFMA(acc, v, wa, wb) do {                                             \
    acc.x = fmaf(v.x, wa.w, acc.x); acc.x = fmaf(v.y, wb.x, acc.x);           \
    acc.x = fmaf(v.z, wb.y, acc.x); acc.x = fmaf(v.w, wb.z, acc.x);           \
    acc.y = fmaf(v.x, wa.z, acc.y); acc.y = fmaf(v.y, wa.w, acc.y);           \
    acc.y = fmaf(v.z, wb.x, acc.y); acc.y = fmaf(v.w, wb.y, acc.y);           \
    acc.z = fmaf(v.x, wa.y, acc.z); acc.z = fmaf(v.y, wa.z, acc.z);           \
    acc.z = fmaf(v.z, wa.w, acc.z); acc.z = fmaf(v.w, wb.x, acc.z);           \
    acc.w = fmaf(v.x, wa.x, acc.w); acc.w = fmaf(v.y, wa.y, acc.w);           \
    acc.w = fmaf(v.z, wa.z, acc.w); acc.w = fmaf(v.w, wa.w, acc.w);           \
} while (0)

#define HFMA(v, cc) do {                                                      \
    const float* wb_ = wr + 64 - rp + 4 * (cc);       /* uniform, 16B-al */   \
    const float4 ws0 = *(const float4*)(wb_);                                 \
    const float4 ws1 = *(const float4*)(wb_ + 4);                             \
    const float4 ws2 = *(const float4*)(wb_ + 8);                             \
    const float4 ws3 = *(const float4*)(wb_ + 12);                            \
    const float4 ws4 = *(const float4*)(wb_ + 16);                            \
    GFMA(oA, v, ws3, ws4);                                                    \
    GFMA(oB, v, ws2, ws3);                                                    \
    GFMA(oC, v, ws1, ws2);                                                    \
    GFMA(oD, v, ws0, ws1);                                                    \
} while (0)

        float4 vA, vB;
        HLOAD(vA, 0);
        int c = 0;
        for (;;) {
            if (c + 1 < C) HLOAD(vB, c + 1);
            HFMA(vA, c);
            if (++c >= C) break;
            if (c + 1 < C) HLOAD(vA, c + 1);
            HFMA(vB, c);
            if (++c >= C) break;
        }
#undef HLOAD
#undef HFMA

        float* __restrict__ op = tmp + ((size_t)plane << 16) + ((size_t)row << 8) + xg;
        *(float4*)(op)      = oA;
        *(float4*)(op + 4)  = oB;
        *(float4*)(op + 8)  = oC;
        *(float4*)(op + 12) = oD;
    }
}

// Vertical pass: persistent waves + ticket queue. Item = 16-row x 256 tile.
// Lane owns 4 px (float4, fully coalesced rows); double-buffered 8-row chunk
// prefetch; weights wave-uniform from global. ZERO LDS.
__global__ __launch_bounds__(256, 2) void vpass(const float* __restrict__ tmp,
                                                const float* __restrict__ wpadV,
                                                const int* __restrict__ steps,
                                                const float* __restrict__ sigmas,
                                                float* __restrict__ out,
                                                unsigned int* __restrict__ tick) {
    const int lane = threadIdx.x & 63;
    for (;;) {
        unsigned int t;
        if (lane == 0) t = atomicAdd(tick, 1u);
        t = (unsigned int)__builtin_amdgcn_readfirstlane((int)t);
        if (t >= NITEMS_V) return;
        const int plane = (int)(t >> 4);
        const int tile  = (int)(t & 15u);
        const int b = plane / NC;
        const float sg = sigmas[steps[b]];
        const int rp = ((int)ceilf(3.0f * sg) + 3) & ~3;
        const int NI = 2 + (rp >> 2);                  // 8-row chunks
        const int yt = tile * 16;
        const int x0 = lane * 4;
        const float* __restrict__ plptr = tmp + ((size_t)plane << 16);
        const float* __restrict__ wr = wpadV + b * WPV;    // uniform

        float4 acc[16];
#pragma unroll
        for (int j = 0; j < 16; ++j) acc[j] = make_float4(0.f, 0.f, 0.f, 0.f);

#define VLOAD(dst, itv) do {                                                  \
    const int i0_ = yt - rp + 8 * (itv);                                      \
    _Pragma("unroll")                                                         \
    for (int di = 0; di < 8; ++di)                                            \
        dst[di] = *(const float4*)(plptr + ((size_t)refl(i0_ + di) << 8) + x0); \
} while (0)

#define VFMA(src, itv) do {                                                   \
    const int s0_ = 72 - rp + 8 * (itv);                                      \
    float wv[24];                                                             \
    _Pragma("unroll")                                                         \
    for (int k = 0; k < 6; ++k)                                               \
        *(float4*)&wv[4 * k] = *(const float4*)(wr + s0_ - 12 + 4 * k);       \
    _Pragma("unroll")                                                         \
    for (int di = 0; di < 8; ++di) {                                          \
        const float4 v = src[di];                                             \
        _Pragma("unroll")                                                     \
        for (int j = 0; j < 16; ++j) {                                        \
            const float w = wv[16 + di - j];       /* tap (i0+di)-(yt+j) */   \
            acc[j].x = fmaf(v.x, w, acc[j].x);                                \
            acc[j].y = fmaf(v.y, w, acc[j].y);                                \
            acc[j].z = fmaf(v.z, w, acc[j].z);                                \
            acc[j].w = fmaf(v.w, w, acc[j].w);                                \
        }                                                                     \
    }                                                                         \
} while (0)

        float4 va[8], vb[8];
        VLOAD(va, 0);
        int it = 0;
        for (;;) {
            if (it + 1 < NI) VLOAD(vb, it + 1);    // prefetch under va's FMAs
            VFMA(va, it);
            ++it; if (it >= NI) break;
            if (it + 1 < NI) VLOAD(va, it + 1);    // prefetch under vb's FMAs
            VFMA(vb, it);
            ++it; if (it >= NI) break;
        }
#undef VLOAD
#undef VFMA

        float* __restrict__ outp = out + ((size_t)plane << 16) + x0;
#pragma unroll
        for (int j = 0; j < 16; ++j)
            *(float4*)(outp + ((size_t)(yt + j) << 8)) = acc[j];
    }
}

extern "C" void kernel_launch(void* const* d_in, const int* in_sizes, int n_in,
                              void* d_out, int out_size, void* d_ws, size_t ws_size,
                              hipStream_t stream) {
    const float* x      = (const float*)d_in[0];
    const int*   steps  = (const int*)d_in[1];
    const float* sigmas = (const float*)d_in[2];
    float* out = (float*)d_out;
    const int B = in_sizes[1];              // 64

    unsigned int* tick = (unsigned int*)d_ws;                      // [0,16): 2 counters
    float* wpadH = (float*)((char*)d_ws + 16);                     // B*WPH floats
    float* wpadV = wpadH + (size_t)B * WPH;                        // B*WPV floats
    float* tmp   = wpadV + (size_t)B * WPV;                        // B*C*H*W floats

    hipMemsetAsync(tick, 0, 16, stream);
    wgen<<<dim3(B), dim3(64), 0, stream>>>(steps, sigmas, wpadH, wpadV);
    hpass<<<dim3(1024), dim3(256), 0, stream>>>(x, wpadH, steps, sigmas, tmp, tick);
    vpass<<<dim3(512), dim3(256), 0, stream>>>(tmp, wpadV, steps, sigmas, out, tick + 1);
}

// Round 8
// 139.768 us; speedup vs baseline: 2.0159x; 2.0159x over previous
//
#include <hip/hip_runtime.h>

#define RMAX 60
#define KTAPS 121          // 2*RMAX+1
#define WPH 160            // hpass weights: center 79 (taps at [19,139]), zeros outside
#define WPV 160            // vpass weights: center 76 (taps at [16,136]), zeros outside
#define NC 3
#define NH 256
#define NW 256
#define NPLANE (64 * NC)   // 192
#define HPB 16             // hpass blocks per plane (16 x 4 waves = 64 x 4-row tiles)
#define VPB 8              // vpass blocks per plane (8 x 4 waves = 32 x 8-row tiles)

__device__ __forceinline__ int refl(int q) {
    // jnp.pad mode='reflect'; valid for q in (-NH, 2*NH-1). Branch-free.
    q = q < 0 ? -q : q;
    int d = (NH - 1) - q;
    d = d < 0 ? -d : d;
    return (NH - 1) - d;
}

// One block (1 wave) per sample: normalized kernel in two padded layouts.
__global__ void wgen(const int* __restrict__ steps, const float* __restrict__ sigmas,
                     float* __restrict__ wpadH, float* __restrict__ wpadV) {
    const int b = blockIdx.x;
    const int t = threadIdx.x;               // 0..63
    const float sg = sigmas[steps[b]];
    const float r = ceilf(3.0f * sg);
    const float inv2s2 = 0.5f / (sg * sg);
    const float o0 = (float)(t - RMAX);                  // tap t-60
    float w0 = (fabsf(o0) <= r) ? expf(-o0 * o0 * inv2s2) : 0.0f;
    const float o1 = (float)(t + 4);                     // tap t+4
    const int t1 = t + 64;
    float w1 = (t1 < KTAPS && fabsf(o1) <= r) ? expf(-o1 * o1 * inv2s2) : 0.0f;
    float s = w0 + w1;
#pragma unroll
    for (int off = 32; off > 0; off >>= 1) s += __shfl_down(s, off);
    const float inv = 1.0f / __shfl(s, 0);
    // H layout: center 79. rh[79+o] = tap o. taps occupy [19,139].
    float* rh = wpadH + b * WPH;
    if (t < 19) rh[t] = 0.0f;                          // [0,19)
    rh[19 + t] = w0 * inv;                             // [19,83)  taps -60..3
    rh[83 + t] = w1 * inv;                             // [83,147) taps 4..60, 0 beyond
    if (t < 13) rh[147 + t] = 0.0f;                    // [147,160)
    // V layout: center 76. taps occupy [16,136].
    float* rv = wpadV + b * WPV;
    if (t < 16) rv[t] = 0.0f;                          // [0,16)
    rv[16 + t] = w0 * inv;                             // [16,80)
    rv[80 + t] = w1 * inv;                             // [80,144)
    if (t < 16) rv[144 + t] = 0.0f;                    // [144,160)
}

// Horizontal pass: static grid, lane owns 16 consecutive px of one row
// (4 x 16-lane groups = 4 rows per wave). Data: float4 window from global
// (L1-heavy reuse). Weights: uniform ds_read broadcast from LDS. No barriers
// in the hot path, no data LDS -> high residency.
__global__ __launch_bounds__(256, 2) void hpass(const float* __restrict__ in,
                                                const float* __restrict__ wpadH,
                                                const int* __restrict__ steps,
                                                const float* __restrict__ sigmas,
                                                float* __restrict__ tmp) {
    __shared__ __align__(16) float wl[WPH];
    const int nwg = NPLANE * HPB;                      // 3072, %8==0
    const int pb = blockIdx.x;
    const int lbid = (pb & 7) * (nwg >> 3) + (pb >> 3);
    const int plane = lbid >> 4;                       // /HPB
    const int b = plane / NC;
    const int t = threadIdx.x;
    const int wave = t >> 6, lane = t & 63;
    if (t < WPH / 4) ((float4*)wl)[t] = ((const float4*)(wpadH + b * WPH))[t];
    __syncthreads();

    const float sg = sigmas[steps[b]];
    const int rp = ((int)ceilf(3.0f * sg) + 3) & ~3;
    const int tile = (lbid & 15) * 4 + wave;           // 0..63
    const int row = tile * 4 + (lane >> 4);
    const int xg = (lane & 15) << 4;
    const float* __restrict__ rowp = in + ((size_t)plane << 16) + ((size_t)row << 8);
    float4 oA = make_float4(0.f, 0.f, 0.f, 0.f), oB = oA, oC = oA, oD = oA;
    const int C = 4 + (rp >> 1);        // float4 input chunks

#define HLOAD(dst, cc) do {                                                   \
    const int p0_ = xg - rp + 4 * (cc);                                       \
    if (p0_ >= 0 && p0_ <= NW - 4) {                                          \
        dst = *(const float4*)(rowp + p0_);                                   \
    } else {                                                                  \
        dst.x = rowp[refl(p0_)];     dst.y = rowp[refl(p0_ + 1)];             \
        dst.z = rowp[refl(p0_ + 2)]; dst.w = rowp[refl(p0_ + 3)];             \
    }                                                                         \
} while (0)

#define GFMA(acc, v, wa, wb) do {                                             \
    acc.x = fmaf(v.x, wa.w, acc.x); acc.x = fmaf(v.y, wb.x, acc.x);           \
    acc.x = fmaf(v.z, wb.y, acc.x); acc.x = fmaf(v.w, wb.z, acc.x);           \
    acc.y = fmaf(v.x, wa.z, acc.y); acc.y = fmaf(v.y, wa.w, acc.y);           \
    acc.y = fmaf(v.z, wb.x, acc.y); acc.y = fmaf(v.w, wb.y, acc.y);           \
    acc.z = fmaf(v.x, wa.y, acc.z); acc.z = fmaf(v.y, wa.z, acc.z);           \
    acc.z = fmaf(v.z, wa.w, acc.z); acc.z = fmaf(v.w, wb.x, acc.z);           \
    acc.w = fmaf(v.x, wa.x, acc.w); acc.w = fmaf(v.y, wa.y, acc.w);           \
    acc.w = fmaf(v.z, wa.z, acc.w); acc.w = fmaf(v.w, wa.w, acc.w);           \
} while (0)

#define HFMA(v, cc) do {                                                      \
    const float* wb_ = wl + 64 - rp + 4 * (cc);       /* uniform, 16B-al */   \
    const float4 ws0 = *(const float4*)(wb_);                                 \
    const float4 ws1 = *(const float4*)(wb_ + 4);                             \
    const float4 ws2 = *(const float4*)(wb_ + 8);                             \
    const float4 ws3 = *(const float4*)(wb_ + 12);                            \
    const float4 ws4 = *(const float4*)(wb_ + 16);                            \
    GFMA(oA, v, ws3, ws4);                                                    \
    GFMA(oB, v, ws2, ws3);                                                    \
    GFMA(oC, v, ws1, ws2);                                                    \
    GFMA(oD, v, ws0, ws1);                                                    \
} while (0)

    float4 vA, vB;
    HLOAD(vA, 0);
    int c = 0;
    for (;;) {
        if (c + 1 < C) HLOAD(vB, c + 1);
        HFMA(vA, c);
        if (++c >= C) break;
        if (c + 1 < C) HLOAD(vA, c + 1);
        HFMA(vB, c);
        if (++c >= C) break;
    }
#undef HLOAD
#undef HFMA

    float* __restrict__ op = tmp + ((size_t)plane << 16) + ((size_t)row << 8) + xg;
    *(float4*)(op)      = oA;
    *(float4*)(op + 4)  = oB;
    *(float4*)(op + 8)  = oC;
    *(float4*)(op + 12) = oD;
}

// Vertical pass: static grid, 8-row x 256 tile per wave (acc[8] in VGPRs),
// double-buffered 4-row chunk prefetch, weights via uniform LDS reads.
__global__ __launch_bounds__(256, 2) void vpass(const float* __restrict__ tmp,
                                                const float* __restrict__ wpadV,
                                                const int* __restrict__ steps,
                                                const float* __restrict__ sigmas,
                                                float* __restrict__ out) {
    __shared__ __align__(16) float wl[WPV];
    const int nwg = NPLANE * VPB;                      // 1536, %8==0
    const int pb = blockIdx.x;
    const int lbid = (pb & 7) * (nwg >> 3) + (pb >> 3);
    const int plane = lbid >> 3;                       // /VPB
    const int b = plane / NC;
    const int t = threadIdx.x;
    const int wave = t >> 6, lane = t & 63;
    if (t < WPV / 4) ((float4*)wl)[t] = ((const float4*)(wpadV + b * WPV))[t];
    __syncthreads();

    const float sg = sigmas[steps[b]];
    const int rp = ((int)ceilf(3.0f * sg) + 3) & ~3;
    const int NI4 = 2 + (rp >> 1);                     // 4-row chunks (even)
    const int tile = (lbid & 7) * 4 + wave;            // 0..31
    const int yt = tile * 8;
    const int x0 = lane * 4;
    const float* __restrict__ plptr = tmp + ((size_t)plane << 16);

    float4 acc[8];
#pragma unroll
    for (int j = 0; j < 8; ++j) acc[j] = make_float4(0.f, 0.f, 0.f, 0.f);

#define VLOAD(dst, itv) do {                                                  \
    const int i0_ = yt - rp + 4 * (itv);                                      \
    _Pragma("unroll")                                                         \
    for (int di = 0; di < 4; ++di)                                            \
        dst[di] = *(const float4*)(plptr + ((size_t)refl(i0_ + di) << 8) + x0); \
} while (0)

#define VFMA(src, itv) do {                                                   \
    const int s0_ = 68 - rp + 4 * (itv);              /* aligned, >=8 */      \
    float wv[12];                                                             \
    _Pragma("unroll")                                                         \
    for (int k = 0; k < 3; ++k)                                               \
        *(float4*)&wv[4 * k] = *(const float4*)&wl[s0_ + 4 * k];              \
    _Pragma("unroll")                                                         \
    for (int di = 0; di < 4; ++di) {                                          \
        const float4 v = src[di];                                             \
        _Pragma("unroll")                                                     \
        for (int j = 0; j < 8; ++j) {                                         \
            const float w = wv[8 + di - j];        /* tap (i0+di)-(yt+j) */   \
            acc[j].x = fmaf(v.x, w, acc[j].x);                                \
            acc[j].y = fmaf(v.y, w, acc[j].y);                                \
            acc[j].z = fmaf(v.z, w, acc[j].z);                                \
            acc[j].w = fmaf(v.w, w, acc[j].w);                                \
        }                                                                     \
    }                                                                         \
} while (0)

    float4 va[4], vb[4];
    VLOAD(va, 0);
    int it = 0;
    for (;;) {
        if (it + 1 < NI4) VLOAD(vb, it + 1);    // prefetch under va's FMAs
        VFMA(va, it);
        ++it; if (it >= NI4) break;
        if (it + 1 < NI4) VLOAD(va, it + 1);    // prefetch under vb's FMAs
        VFMA(vb, it);
        ++it; if (it >= NI4) break;
    }
#undef VLOAD
#undef VFMA

    float* __restrict__ outp = out + ((size_t)plane << 16) + x0;
#pragma unroll
    for (int j = 0; j < 8; ++j)
        *(float4*)(outp + ((size_t)(yt + j) << 8)) = acc[j];
}

extern "C" void kernel_launch(void* const* d_in, const int* in_sizes, int n_in,
                              void* d_out, int out_size, void* d_ws, size_t ws_size,
                              hipStream_t stream) {
    const float* x      = (const float*)d_in[0];
    const int*   steps  = (const int*)d_in[1];
    const float* sigmas = (const float*)d_in[2];
    float* out = (float*)d_out;
    const int B = in_sizes[1];              // 64

    float* wpadH = (float*)d_ws;                                   // B*WPH floats
    float* wpadV = wpadH + (size_t)B * WPH;                        // B*WPV floats
    float* tmp   = wpadV + (size_t)B * WPV;                        // B*C*H*W floats

    wgen<<<dim3(B), dim3(64), 0, stream>>>(steps, sigmas, wpadH, wpadV);
    hpass<<<dim3(NPLANE * HPB), dim3(256), 0, stream>>>(x, wpadH, steps, sigmas, tmp);
    vpass<<<dim3(NPLANE * VPB), dim3(256), 0, stream>>>(tmp, wpadV, steps, sigmas, out);
}